// Round 1
// baseline (151.204 us; speedup 1.0000x reference)
//
#include <hip/hip_runtime.h>
#include <math.h>

#define EMBED     128
#define NUM_C     64
#define EPS       1e-5f

#define WAVES_PER_BLOCK 4
#define NODES_PER_WAVE  8
#define NODES_PER_BLOCK (WAVES_PER_BLOCK * NODES_PER_WAVE)   // 32
#define LDSROW 132   // 128 + 4 pad: keeps ds_read_b128 16B-aligned, banks uniformly loaded

__global__ __launch_bounds__(256) void cd_main(
    const float* __restrict__ node_repr,   // [N,128]
    const float* __restrict__ mask,        // [N,1]
    const float* __restrict__ cent,        // [64,128]
    float* __restrict__ out,               // [64 + N*64]
    float* __restrict__ acc,               // [64 sums, 1 mask-sum]
    int N)
{
    __shared__ float sc[NUM_C * LDSROW];

    const int tid = threadIdx.x;

    // Stage centroids -> LDS (2048 float4, coalesced global read)
    for (int f = tid; f < NUM_C * EMBED / 4; f += 256) {
        const int c  = f >> 5;       // f / 32
        const int e4 = f & 31;       // f % 32
        float4 v = ((const float4*)cent)[f];
        *(float4*)&sc[c * LDSROW + e4 * 4] = v;
    }
    __syncthreads();

    const int lane  = tid & 63;       // = centroid index for this lane
    const int wave  = tid >> 6;
    const int node0 = blockIdx.x * NODES_PER_BLOCK + wave * NODES_PER_WAVE;

    // sv = ||centroid_lane||^2  (row read, same bank pattern as main loop)
    float sv = 0.f;
    #pragma unroll
    for (int e = 0; e < EMBED; e += 4) {
        float4 c4 = *(const float4*)&sc[lane * LDSROW + e];
        sv += c4.x * c4.x + c4.y * c4.y + c4.z * c4.z + c4.w * c4.w;
    }

    float su[NODES_PER_WAVE];
    float dot[NODES_PER_WAVE];
    float mk[NODES_PER_WAVE];

    // Per-node ||u||^2 via cooperative wave reduce (lane reads float2 -> 128 elems)
    #pragma unroll
    for (int j = 0; j < NODES_PER_WAVE; ++j) {
        int n = node0 + j;
        int nc = n < N ? n : N - 1;                 // clamp for safe load
        const float2 u2 = *(const float2*)&node_repr[(long)nc * EMBED + lane * 2];
        float s = u2.x * u2.x + u2.y * u2.y;
        #pragma unroll
        for (int k = 32; k; k >>= 1) s += __shfl_xor(s, k, 64);
        su[j]  = s;
        dot[j] = 0.f;
        mk[j]  = mask[nc];
    }

    // Main dot loop: 1 LDS b128 read amortized over 8 nodes (8*4 = 32 FMA)
    for (int e = 0; e < EMBED; e += 4) {
        float4 c4 = *(const float4*)&sc[lane * LDSROW + e];
        #pragma unroll
        for (int j = 0; j < NODES_PER_WAVE; ++j) {
            int n = node0 + j;
            int nc = n < N ? n : N - 1;
            float4 u4 = *(const float4*)&node_repr[(long)nc * EMBED + e];
            dot[j] += u4.x * c4.x + u4.y * c4.y + u4.z * c4.z + u4.w * c4.w;
        }
    }

    // Epilogue: distance, masked write, per-wave graph accumulation
    float gacc = 0.f;
    #pragma unroll
    for (int j = 0; j < NODES_PER_WAVE; ++j) {
        int n = node0 + j;
        if (n < N) {
            float sq = su[j] + sv - 2.f * dot[j];
            sq = fmaxf(sq, 0.f);
            float denom = fmaxf((1.f - su[j]) * (1.f - sv), EPS);
            float t = fmaxf(2.f * sq / denom, EPS);
            // arccosh(1+t) = log1p(t + sqrt(t*(t+2))) -- stable for small t
            float dist = log1pf(t + sqrtf(t * (t + 2.f)));
            float v = dist * mk[j];
            out[NUM_C + (long)n * NUM_C + lane] = v;   // coalesced 256B/wave store
            gacc += v;
        }
    }

    atomicAdd(&acc[lane], gacc);       // 64 distinct addresses per wave
    if (lane == 0) {
        float ms = 0.f;
        #pragma unroll
        for (int j = 0; j < NODES_PER_WAVE; ++j)
            if (node0 + j < N) ms += mk[j];
        atomicAdd(&acc[NUM_C], ms);
    }
}

__global__ void cd_fin(const float* __restrict__ acc, float* __restrict__ out)
{
    int c = threadIdx.x;
    if (c < NUM_C) out[c] = acc[c] / acc[NUM_C];
}

extern "C" void kernel_launch(void* const* d_in, const int* in_sizes, int n_in,
                              void* d_out, int out_size, void* d_ws, size_t ws_size,
                              hipStream_t stream) {
    const float* node_repr = (const float*)d_in[0];
    const float* mask      = (const float*)d_in[1];
    const float* cent      = (const float*)d_in[2];
    float* out = (float*)d_out;
    float* acc = (float*)d_ws;

    const int N = in_sizes[0] / EMBED;

    // ws is poisoned 0xAA before every launch -> zero the accumulators
    hipMemsetAsync(acc, 0, (NUM_C + 1) * sizeof(float), stream);

    const int blocks = (N + NODES_PER_BLOCK - 1) / NODES_PER_BLOCK;
    cd_main<<<blocks, 256, 0, stream>>>(node_repr, mask, cent, out, acc, N);
    cd_fin<<<1, 64, 0, stream>>>(acc, out);
}

// Round 2
// 127.173 us; speedup vs baseline: 1.1890x; 1.1890x over previous
//
#include <hip/hip_runtime.h>
#include <math.h>

#define EMBED  128
#define NUM_C  64
#define EPS    1e-5f
#define LDSROW 132          // 128 + 4 pad: b128 row reads stay bank-balanced (8 words/bank)
#define NPB    32           // nodes per block
#define NPW    8            // nodes per wave (4 waves/block)

__global__ __launch_bounds__(256) void cd_main(
    const float* __restrict__ node_repr,   // [N,128]
    const float* __restrict__ mask,        // [N,1]
    const float* __restrict__ cent,        // [64,128]
    float* __restrict__ out,               // [64 + N*64]
    float* __restrict__ colsum,            // [nb*64] partials  (or acc[64] atomic mode)
    float* __restrict__ msum,              // [nb] mask partials (or &acc[64])
    int N, int atomicMode)
{
    __shared__ float sc[NUM_C * LDSROW];   // 33792 B centroids (padded)
    __shared__ float nt[NPB * EMBED];      // 16384 B node tile (unpadded, broadcast reads)
    __shared__ float wacc[4 * NUM_C];
    __shared__ float wmask[4];

    const int tid       = threadIdx.x;
    const int node_base = blockIdx.x * NPB;

    // Stage centroids -> LDS: 2048 coalesced float4
    for (int f = tid; f < NUM_C * EMBED / 4; f += 256) {
        const int c = f >> 5, e4 = f & 31;
        float4 v = ((const float4*)cent)[f];
        *(float4*)&sc[c * LDSROW + e4 * 4] = v;
    }
    // Stage node tile -> LDS: contiguous 16 KB, 1024 coalesced float4
    {
        const int maxi = N * (EMBED / 4);
        for (int f = tid; f < NPB * EMBED / 4; f += 256) {
            int gi = node_base * (EMBED / 4) + f;
            float4 v = ((const float4*)node_repr)[gi < maxi ? gi : maxi - 1];
            *(float4*)&nt[f * 4] = v;
        }
    }
    __syncthreads();

    const int lane = tid & 63;             // = centroid index
    const int wave = tid >> 6;
    const int j0   = wave * NPW;           // first node (within tile) for this wave

    // sv = ||centroid_lane||^2
    float sv = 0.f;
    #pragma unroll
    for (int e = 0; e < EMBED; e += 4) {
        float4 c4 = *(const float4*)&sc[lane * LDSROW + e];
        sv = fmaf(c4.x, c4.x, fmaf(c4.y, c4.y, fmaf(c4.z, c4.z, fmaf(c4.w, c4.w, sv))));
    }

    float su[NPW], dot[NPW], mk[NPW];

    // su[j] = ||u_j||^2 : cooperative wave reduce from LDS (float2/lane, bank-balanced)
    #pragma unroll
    for (int j = 0; j < NPW; ++j) {
        float2 u2 = *(const float2*)&nt[(j0 + j) * EMBED + lane * 2];
        float s = fmaf(u2.x, u2.x, u2.y * u2.y);
        #pragma unroll
        for (int k = 32; k; k >>= 1) s += __shfl_xor(s, k, 64);
        su[j]  = s;
        dot[j] = 0.f;
        int n  = node_base + j0 + j;
        mk[j]  = mask[n < N ? n : N - 1];
    }

    // Main loop: 1 bank-balanced b128 (centroid) + 8 broadcast b128 (nodes) + 32 fmac
    #pragma unroll 8
    for (int e = 0; e < EMBED; e += 4) {
        float4 c4 = *(const float4*)&sc[lane * LDSROW + e];
        #pragma unroll
        for (int j = 0; j < NPW; ++j) {
            float4 u4 = *(const float4*)&nt[(j0 + j) * EMBED + e];
            dot[j] = fmaf(u4.x, c4.x, fmaf(u4.y, c4.y,
                     fmaf(u4.z, c4.z, fmaf(u4.w, c4.w, dot[j]))));
        }
    }

    // Epilogue: distance, masked store (coalesced 256B/wave), per-wave column sums
    float gacc = 0.f;
    #pragma unroll
    for (int j = 0; j < NPW; ++j) {
        int n = node_base + j0 + j;
        float sq    = fmaxf(su[j] + sv - 2.f * dot[j], 0.f);
        float denom = fmaxf((1.f - su[j]) * (1.f - sv), EPS);
        float t     = fmaxf(2.f * sq / denom, EPS);
        float dist  = log1pf(t + sqrtf(t * (t + 2.f)));   // arccosh(1+t), stable
        float v     = dist * mk[j];
        if (n < N) {
            out[NUM_C + (long)n * NUM_C + lane] = v;
            gacc += v;
        }
    }

    wacc[wave * NUM_C + lane] = gacc;
    if (lane == 0) {
        float ms = 0.f;
        #pragma unroll
        for (int j = 0; j < NPW; ++j)
            if (node_base + j0 + j < N) ms += mk[j];
        wmask[wave] = ms;
    }
    __syncthreads();

    if (wave == 0) {
        float s = wacc[lane] + wacc[NUM_C + lane] + wacc[2 * NUM_C + lane] + wacc[3 * NUM_C + lane];
        if (atomicMode) {
            atomicAdd(&colsum[lane], s);
            if (lane == 0)
                atomicAdd(&msum[0], wmask[0] + wmask[1] + wmask[2] + wmask[3]);
        } else {
            colsum[(long)blockIdx.x * NUM_C + lane] = s;
            if (lane == 0)
                msum[blockIdx.x] = wmask[0] + wmask[1] + wmask[2] + wmask[3];
        }
    }
}

// Reduce per-block partials -> out[0..63]
__global__ __launch_bounds__(256) void cd_fin(
    const float* __restrict__ colsum, const float* __restrict__ msum,
    float* __restrict__ out, int nb)
{
    __shared__ float red[256];
    __shared__ float mtot_s;
    const int tid = threadIdx.x;

    // total mask sum
    float m = 0.f;
    for (int b = tid; b < nb; b += 256) m += msum[b];
    #pragma unroll
    for (int k = 32; k; k >>= 1) m += __shfl_xor(m, k, 64);
    if ((tid & 63) == 0) red[tid >> 6] = m;
    __syncthreads();
    if (tid == 0) mtot_s = red[0] + red[1] + red[2] + red[3];
    __syncthreads();

    // column sums: thread (q,c) strides blocks by 4, coalesced 256B rows
    const int c = tid & 63, q = tid >> 6;
    float s = 0.f;
    for (int b = q; b < nb; b += 4) s += colsum[(long)b * NUM_C + c];
    red[tid] = s;
    __syncthreads();
    if (q == 0)
        out[c] = (red[c] + red[64 + c] + red[128 + c] + red[192 + c]) / mtot_s;
}

// atomic-mode fallback helpers
__global__ void cd_zero(float* acc) { if (threadIdx.x < NUM_C + 1) acc[threadIdx.x] = 0.f; }
__global__ void cd_fin_atomic(const float* __restrict__ acc, float* __restrict__ out) {
    int c = threadIdx.x;
    if (c < NUM_C) out[c] = acc[c] / acc[NUM_C];
}

extern "C" void kernel_launch(void* const* d_in, const int* in_sizes, int n_in,
                              void* d_out, int out_size, void* d_ws, size_t ws_size,
                              hipStream_t stream) {
    const float* node_repr = (const float*)d_in[0];
    const float* mask      = (const float*)d_in[1];
    const float* cent      = (const float*)d_in[2];
    float* out = (float*)d_out;

    const int N  = in_sizes[0] / EMBED;
    const int nb = (N + NPB - 1) / NPB;
    const size_t needed = (size_t)nb * NUM_C * sizeof(float) + (size_t)nb * sizeof(float);

    if (ws_size >= needed) {
        float* colsum = (float*)d_ws;
        float* msum   = colsum + (size_t)nb * NUM_C;
        cd_main<<<nb, 256, 0, stream>>>(node_repr, mask, cent, out, colsum, msum, N, 0);
        cd_fin<<<1, 256, 0, stream>>>(colsum, msum, out, nb);
    } else {
        float* acc = (float*)d_ws;   // 65 floats
        cd_zero<<<1, 128, 0, stream>>>(acc);
        cd_main<<<nb, 256, 0, stream>>>(node_repr, mask, cent, out, acc, acc + NUM_C, N, 1);
        cd_fin_atomic<<<1, 64, 0, stream>>>(acc, out);
    }
}